// Round 14
// baseline (116.761 us; speedup 1.0000x reference)
//
#include <hip/hip_runtime.h>

#define LL 16
#define CC 32
#define HIDN 16
#define HH 64
#define WW 64
#define HW 4096    // 64*64
#define NCHUNK 40  // (t, k-chunk-of-4) pairs

// ws layout (floats):
#define CUM_OFF  0                                   // 131072
#define U_OFF    (LL * 2 * HW)                       // 1048576
#define V_OFF    (U_OFF + LL * HIDN * HW)            // 1048576
#define IMGC_OFF (V_OFF + LL * HIDN * HW)            // bf16 ch-grouped: LL*CC*HW/2 = 1048576

// ---- chunk tables, SORTED by k-chunk (KC) then t, for XCD locality ----
__device__ const int T_SORT[NCHUNK] = {
    0,1,2,3,4,5,6,7,8,9,10,11,12,13,14,15,
    4,5,6,7,8,9,10,11,12,13,14,15,
    8,9,10,11,12,13,14,15,
    12,13,14,15 };
__device__ const int KC_SORT[NCHUNK] = {
    0,0,0,0,0,0,0,0,0,0,0,0,0,0,0,0,
    1,1,1,1,1,1,1,1,1,1,1,1,
    2,2,2,2,2,2,2,2,
    3,3,3,3 };

__device__ inline unsigned short f2bf(float f) {   // RNE fp32 -> bf16
    unsigned u = __float_as_uint(f);
    unsigned r = (u + 0x7fffu + ((u >> 16) & 1u)) >> 16;
    return (unsigned short)r;
}
__device__ inline float bflo(unsigned u) { return __uint_as_float(u << 16); }
__device__ inline float bfhi(unsigned u) { return __uint_as_float(u & 0xffff0000u); }

// ---------------- prep (+ fused cumsum row): U/V, bf16 ch-grouped copy --------
// grid: (16 px-tiles, 17). y<16: prep for frame l=y. y==16: cumsum of flows.
__global__ __launch_bounds__(256) void prep_kernel(const float* __restrict__ images,
                                                   const float* __restrict__ flows,
                                                   const float* __restrict__ w1,
                                                   const float* __restrict__ b1,
                                                   float* __restrict__ ws) {
    const int tid = threadIdx.x;

    if (blockIdx.y == LL) {
        // ---- cumsum of flows over L: thread g handles planes p=0 and p=1 ----
        const int g = blockIdx.x * 256 + tid;     // 0..4095
        float* cum = ws + CUM_OFF;
        float a0 = 0.0f, a1 = 0.0f;
#pragma unroll
        for (int l = 0; l < LL; ++l) {
            a0 += flows[l * 2 * HW + g];
            a1 += flows[l * 2 * HW + HW + g];
            cum[l * 2 * HW + g]      = a0;
            cum[l * 2 * HW + HW + g] = a1;
        }
        return;
    }

    __shared__ float w1s[HIDN * 2 * CC];
    ((float4*)w1s)[tid] = ((const float4*)w1)[tid];
    __syncthreads();

    const int l  = blockIdx.y;
    const int px = blockIdx.x * 256 + tid;
    const float* img = images + (size_t)l * CC * HW;

    float x[CC];
#pragma unroll
    for (int c = 0; c < CC; ++c) x[c] = img[c * HW + px];   // coalesced

    float u[HIDN], v[HIDN];
#pragma unroll
    for (int o = 0; o < HIDN; ++o) { u[o] = 0.0f; v[o] = b1[o]; }
#pragma unroll
    for (int c = 0; c < CC; ++c) {
#pragma unroll
        for (int o = 0; o < HIDN; ++o) {
            u[o] = fmaf(w1s[o * 64 + c],      x[c], u[o]);
            v[o] = fmaf(w1s[o * 64 + CC + c], x[c], v[o]);
        }
    }

    float* Up = ws + U_OFF + (size_t)l * HIDN * HW + px;
    float* Vp = ws + V_OFF + (size_t)l * HIDN * HW + px;
#pragma unroll
    for (int o = 0; o < HIDN; ++o) {
        Up[o * HW] = u[o];
        Vp[o * HW] = v[o];
    }

    // bf16 channel-group-8 copy: plane (l*4+cg), 16B per px
    uint4* img4 = (uint4*)(ws + IMGC_OFF);
#pragma unroll
    for (int cg = 0; cg < 4; ++cg) {
        const int c0 = cg * 8;
        unsigned d[4];
#pragma unroll
        for (int q = 0; q < 4; ++q)
            d[q] = (unsigned)f2bf(x[c0 + 2 * q]) | ((unsigned)f2bf(x[c0 + 2 * q + 1]) << 16);
        img4[((size_t)(l * 4 + cg)) * HW + px] = make_uint4(d[0], d[1], d[2], d[3]);
    }
}

// ---------------- fused sample: in-block MLP (LDS) + gathers + atomic out -----
// grid: 2560 linear blocks; s=(i%8)*320+i/8 pins k-chunk windows to XCDs
// phase 1: 256 thr = 4 k-slots x 64 px  -> disp into LDS
// phase 2: 256 thr = 64 px x 4 channel-groups of 8 -> gathers + atomicAdd out
__global__ __launch_bounds__(256, 2) void sample_kernel(const float* __restrict__ ws_in,
                                                        const float* __restrict__ w2,
                                                        const float* __restrict__ b2,
                                                        const float* __restrict__ decay_log,
                                                        float* __restrict__ out) {
    __shared__ float  w2s[2 * HIDN];
    __shared__ float  b2s2[2];
    __shared__ float2 dls[4][64];     // disp per (k-slot, px-lane)

    const int tid = threadIdx.x;
    if (tid < 2 * HIDN) w2s[tid] = w2[tid];
    if (tid < 2)        b2s2[tid] = b2[tid];
    __syncthreads();

    const int hwb = blockIdx.x;
    const int s   = (hwb & 7) * 320 + (hwb >> 3);  // XCD-pinning permutation
    const int cid = s >> 6;                        // sorted chunk id 0..39
    const int strip = s & 63;                      // image row
    const int t   = T_SORT[cid];
    const int k0  = KC_SORT[cid] * 4;

    const float* cum = ws_in + CUM_OFF;
    const float* Ub  = ws_in + U_OFF;
    const float* Vb  = ws_in + V_OFF;
    const uint4* img4 = (const uint4*)(ws_in + IMGC_OFF);

    // ---- phase 1: MLP for (k0+kk, px) -> LDS ----
    {
        const int kk  = tid >> 6;            // k slot 0..3
        const int lp  = tid & 63;
        const int px1 = strip * 64 + lp;
        const int k1  = k0 + kk;             // always <= 15 (valid frame)

        const float* up = Ub + (size_t)t  * HIDN * HW + px1;
        const float* vp = Vb + (size_t)k1 * HIDN * HW + px1;

        float res0 = b2s2[0], res1 = b2s2[1];
#pragma unroll
        for (int o = 0; o < HIDN; ++o) {
            float h = fmaxf(up[o * HW] + vp[o * HW], 0.0f);   // coalesced
            res0 = fmaf(w2s[o],        h, res0);
            res1 = fmaf(w2s[HIDN + o], h, res1);
        }

        float dx = (cum[(t * 2)     * HW + px1] - cum[(k1 * 2)     * HW + px1]) + res0;
        float dy = (cum[(t * 2 + 1) * HW + px1] - cum[(k1 * 2 + 1) * HW + px1]) + res1;
        dls[kk][lp] = make_float2(dx, dy);
    }
    __syncthreads();

    // ---- phase 2: gathers ----
    const int lane = tid & 63;        // x coord
    const int cg   = tid >> 6;        // channel group (one per wave)
    const int px   = strip * 64 + lane;

    const float lam = expf(decay_log[0]);
    const float bgx = (float)(2 * lane  + 1) * (1.0f / 64.0f) - 1.0f;
    const float bgy = (float)(2 * strip + 1) * (1.0f / 64.0f) - 1.0f;

    int   off[4][4];
    float cwt[4][4];
#pragma unroll
    for (int dk = 0; dk < 4; ++dk) {
        const int k = k0 + dk;
        const float wtd = (k <= t) ? expf(-lam * (float)(t - k)) : 0.0f;
        float2 d = dls[dk][lane];

        float gx = bgx + d.x;
        float gy = bgy + d.y;

        // wrap x: mod(gx+1, 2) - 1 (floor-mod)
        float xp = gx + 1.0f;
        xp = xp - floorf(xp * 0.5f) * 2.0f;
        float gxw = xp - 1.0f;

        float ix = ((gxw + 1.0f) * 64.0f - 1.0f) * 0.5f;
        float iy = ((gy  + 1.0f) * 64.0f - 1.0f) * 0.5f;

        float ix0f = floorf(ix), iy0f = floorf(iy);
        float fx1 = ix - ix0f, fy1 = iy - iy0f;
        float fx0 = 1.0f - fx1, fy0 = 1.0f - fy1;
        int ix0 = (int)ix0f, iy0 = (int)iy0f;
        int ix1 = ix0 + 1,   iy1 = iy0 + 1;

        int xi[4] = {ix0, ix1, ix0, ix1};
        int yi[4] = {iy0, iy0, iy1, iy1};
        float wwv[4] = {fx0 * fy0, fx1 * fy0, fx0 * fy1, fx1 * fy1};
#pragma unroll
        for (int j = 0; j < 4; ++j) {
            bool valid = (xi[j] >= 0) & (xi[j] < WW) & (yi[j] >= 0) & (yi[j] < HH);
            int xc = min(max(xi[j], 0), WW - 1);
            int yc = min(max(yi[j], 0), HH - 1);
            off[dk][j] = yc * WW + xc;
            cwt[dk][j] = valid ? wwv[j] * wtd : 0.0f;
        }
    }

    // 16 independent dwordx4 gathers (frame k0+dk always a valid frame)
    uint4 q[4][4];
#pragma unroll
    for (int dk = 0; dk < 4; ++dk) {
        const size_t pb = (size_t)((k0 + dk) * 4 + cg) * HW;
#pragma unroll
        for (int j = 0; j < 4; ++j)
            q[dk][j] = img4[pb + off[dk][j]];
    }

    float acc[8];
#pragma unroll
    for (int j = 0; j < 8; ++j) acc[j] = 0.0f;

#pragma unroll
    for (int dk = 0; dk < 4; ++dk) {
#pragma unroll
        for (int j = 0; j < 4; ++j) {
            const float wj = cwt[dk][j];
            const uint4 v = q[dk][j];
            acc[0] = fmaf(wj, bflo(v.x), acc[0]);
            acc[1] = fmaf(wj, bfhi(v.x), acc[1]);
            acc[2] = fmaf(wj, bflo(v.y), acc[2]);
            acc[3] = fmaf(wj, bfhi(v.y), acc[3]);
            acc[4] = fmaf(wj, bflo(v.z), acc[4]);
            acc[5] = fmaf(wj, bfhi(v.z), acc[5]);
            acc[6] = fmaf(wj, bflo(v.w), acc[6]);
            acc[7] = fmaf(wj, bfhi(v.w), acc[7]);
        }
    }

    // accumulate directly into out (<=4 contributing blocks per cell)
    float* Op = out + ((size_t)t * CC + cg * 8) * HW + px;
#pragma unroll
    for (int j = 0; j < 8; ++j) atomicAdd(Op + j * HW, acc[j]);
}

extern "C" void kernel_launch(void* const* d_in, const int* in_sizes, int n_in,
                              void* d_out, int out_size, void* d_ws, size_t ws_size,
                              hipStream_t stream) {
    const float* flows     = (const float*)d_in[0];
    const float* images    = (const float*)d_in[1];
    const float* decay_log = (const float*)d_in[2];
    const float* w1        = (const float*)d_in[3];
    const float* b1        = (const float*)d_in[4];
    const float* w2        = (const float*)d_in[5];
    const float* b2        = (const float*)d_in[6];
    float* out = (float*)d_out;
    float* ws  = (float*)d_ws;

    // zero output (harness poisons with 0xAA before every launch)
    hipMemsetAsync(d_out, 0, (size_t)out_size * sizeof(float), stream);

    // prep (U/V + bf16 copy) with fused cumsum row
    prep_kernel<<<dim3(HW / 256, LL + 1), dim3(256), 0, stream>>>(
        images, flows, w1, b1, ws);

    // fused sample: MLP -> LDS -> gathers -> atomic accumulate into out
    sample_kernel<<<dim3(8 * 320), dim3(256), 0, stream>>>(
        ws, w2, b2, decay_log, out);
}